// Round 5
// baseline (538.394 us; speedup 1.0000x reference)
//
#include <hip/hip_runtime.h>
#include <hip/hip_bf16.h>

#define NT 8
#define MEMC 512
#define HID 256
#define C 128   // IN_C == OUT_C

typedef __attribute__((ext_vector_type(8))) short short8;
typedef __attribute__((ext_vector_type(4))) float f32x4;

__device__ inline short f2bf(float f) {
    union { __hip_bfloat16 b; short s; } u;
    u.b = __float2bfloat16(f);
    return u.s;
}

// ---------------------------------------------------------------------------
// K1: hist+cursor zero (block 0) + generator hidden layers h_wg/h_bg [8][256]
//     (blocks 1..16).  No idx init: k5 masks pad rows via hist counts.
// ---------------------------------------------------------------------------
__global__ __launch_bounds__(256) void k1_init_genh(
    const float* __restrict__ edge_feas,
    const float* __restrict__ wg_w1, const float* __restrict__ wg_b1,
    const float* __restrict__ wg_w2, const float* __restrict__ wg_b2,
    const float* __restrict__ bg_w1, const float* __restrict__ bg_b1,
    const float* __restrict__ bg_w2, const float* __restrict__ bg_b2,
    int* __restrict__ hist, int* __restrict__ cursor,
    float* __restrict__ h_wg, float* __restrict__ h_bg)
{
    int b = blockIdx.x, tid = threadIdx.x;
    if (b == 0) {
        if (tid < NT) { hist[tid] = 0; cursor[tid * 16] = 0; }
        return;
    }
    int gb = b - 1;                          // 0..15
    int t = gb & 7;
    int gen = gb >> 3;
    const float* w1 = gen ? bg_w1 : wg_w1;
    const float* b1 = gen ? bg_b1 : wg_b1;
    const float* w2 = gen ? bg_w2 : wg_w2;
    const float* b2 = gen ? bg_b2 : wg_b2;
    float* hout = gen ? h_bg : h_wg;

    __shared__ float m[MEMC];
    __shared__ float part[4][HID];
    __shared__ float h1[HID];
    m[tid]       = edge_feas[t * MEMC + tid];
    m[tid + 256] = edge_feas[t * MEMC + tid + 256];
    __syncthreads();

    int w = tid >> 6, l = tid & 63;
    // layer 1: K=512, wave w owns k in [w*128, w*128+128)
    {
        float ax = 0.f, ay = 0.f, az = 0.f, aw = 0.f;
        const float* wp = w1 + (size_t)(w * 128) * HID + 4 * l;
        #pragma unroll 8
        for (int k = 0; k < 128; ++k) {
            float4 v = *(const float4*)(wp + (size_t)k * HID);
            float mk = m[w * 128 + k];
            ax += mk * v.x; ay += mk * v.y; az += mk * v.z; aw += mk * v.w;
        }
        *(float4*)&part[w][4 * l] = make_float4(ax, ay, az, aw);
    }
    __syncthreads();
    {
        float s = part[0][tid] + part[1][tid] + part[2][tid] + part[3][tid] + b1[tid];
        h1[tid] = fmaxf(s, 0.f);
    }
    __syncthreads();
    // layer 2: K=256, wave w owns k in [w*64, w*64+64)
    {
        float ax = 0.f, ay = 0.f, az = 0.f, aw = 0.f;
        const float* wp = w2 + (size_t)(w * 64) * HID + 4 * l;
        #pragma unroll 8
        for (int k = 0; k < 64; ++k) {
            float4 v = *(const float4*)(wp + (size_t)k * HID);
            float hk = h1[w * 64 + k];
            ax += hk * v.x; ay += hk * v.y; az += hk * v.z; aw += hk * v.w;
        }
        *(float4*)&part[w][4 * l] = make_float4(ax, ay, az, aw);
    }
    __syncthreads();
    {
        float s = part[0][tid] + part[1][tid] + part[2][tid] + part[3][tid] + b2[tid];
        hout[t * HID + tid] = fmaxf(s, 0.f);
    }
}

// ---------------------------------------------------------------------------
// K2: type histogram (ballot-based) + third layers.
//   W blocks (256): 64 cols each, 4-way K-split, 8 types per load,
//                   written DIRECTLY transposed into Wt[t][n][k].
//   Bias block (1): 128 cols, 2-way K-split, 8 types per load.
// ---------------------------------------------------------------------------
__global__ __launch_bounds__(256) void k2_hist_genw(
    const int* __restrict__ type_vec, int N,
    const float* __restrict__ h_wg, const float* __restrict__ h_bg,
    const float* __restrict__ wg_w3, const float* __restrict__ wg_b3,
    const float* __restrict__ bg_w3, const float* __restrict__ bg_b3,
    int* __restrict__ hist, short* __restrict__ Wt, float* __restrict__ Bias,
    int n_hist_blocks)
{
    int b = blockIdx.x, tid = threadIdx.x;
    __shared__ float sh[2048];
    __shared__ float sp[2048];
    if (b < n_hist_blocks) {
        int lane = tid & 63, wv = tid >> 6;
        int start = b * 1024 + wv * 256;
        int cnt[NT];
        #pragma unroll
        for (int t = 0; t < NT; ++t) cnt[t] = 0;
        #pragma unroll
        for (int c = 0; c < 4; ++c) {
            int n = start + c * 64 + lane;
            int mt = (n < N) ? type_vec[n] : NT;
            #pragma unroll
            for (int t = 0; t < NT; ++t)
                cnt[t] += __popcll(__ballot(mt == t));
        }
        if (lane < NT) atomicAdd(&hist[lane], cnt[lane]);
        return;
    }
    int gb = b - n_hist_blocks;
    if (gb < 256) {
        for (int i = tid; i < 2048; i += 256) sh[i] = h_wg[i];
        __syncthreads();
        int cl = tid & 63, p = tid >> 6;
        int col = gb * 64 + cl;
        float acc[NT];
        #pragma unroll
        for (int t = 0; t < NT; ++t) acc[t] = 0.f;
        const float* wp = wg_w3 + (size_t)(p * 64) * (C * C) + col;
        #pragma unroll 8
        for (int j = 0; j < 64; ++j) {
            float v = wp[(size_t)j * (C * C)];
            #pragma unroll
            for (int t = 0; t < NT; ++t) acc[t] += sh[t * 256 + p * 64 + j] * v;
        }
        #pragma unroll
        for (int t = 0; t < NT; ++t) sp[p * 512 + t * 64 + cl] = acc[t];
        __syncthreads();
        #pragma unroll
        for (int r = 0; r < 2; ++r) {
            int o = tid + 256 * r;               // 0..511
            int t = o >> 6, c2 = o & 63;
            float s = sp[t * 64 + c2] + sp[512 + t * 64 + c2]
                    + sp[1024 + t * 64 + c2] + sp[1536 + t * 64 + c2]
                    + wg_b3[gb * 64 + c2];
            int flat = gb * 64 + c2;             // = k*128 + n
            Wt[t * (C * C) + (flat & 127) * C + (flat >> 7)] = f2bf(s);
        }
        return;
    }
    // bias block
    for (int i = tid; i < 2048; i += 256) sh[i] = h_bg[i];
    __syncthreads();
    int cl = tid & 127, p = tid >> 7;
    float acc[NT];
    #pragma unroll
    for (int t = 0; t < NT; ++t) acc[t] = 0.f;
    const float* wp = bg_w3 + (size_t)(p * 128) * C + cl;
    #pragma unroll 8
    for (int j = 0; j < 128; ++j) {
        float v = wp[(size_t)j * C];
        #pragma unroll
        for (int t = 0; t < NT; ++t) acc[t] += sh[t * 256 + p * 128 + j] * v;
    }
    #pragma unroll
    for (int t = 0; t < NT; ++t) sp[p * 1024 + t * 128 + cl] = acc[t];
    __syncthreads();
    #pragma unroll
    for (int r = 0; r < 4; ++r) {
        int o = tid + 256 * r;                   // 0..1023
        int t = o >> 7, c2 = o & 127;
        Bias[t * C + c2] = sp[t * 128 + c2] + sp[1024 + t * 128 + c2] + bg_b3[c2];
    }
}

// ---------------------------------------------------------------------------
// K4: ballot scatter into type-sorted idx[] (seg 64-aligned, from hist).
//     256 elems/wave, block-aggregated cursor atomics.
// ---------------------------------------------------------------------------
__global__ __launch_bounds__(256) void k4_scatter(
    const int* __restrict__ type_vec, int N,
    const int* __restrict__ hist, int* __restrict__ cursor,
    int* __restrict__ idx)
{
    int b = blockIdx.x, tid = threadIdx.x;
    int lane = tid & 63, wv = tid >> 6;
    __shared__ int pb[4][NT];

    int seg[NT];
    {
        int s = 0;
        #pragma unroll
        for (int t = 0; t < NT; ++t) { seg[t] = s; s += ((hist[t] + 63) >> 6) << 6; }
    }
    int start = b * 1024 + wv * 256;

    // pass 1: per-wave counts
    int cnt[NT];
    #pragma unroll
    for (int t = 0; t < NT; ++t) cnt[t] = 0;
    #pragma unroll
    for (int c = 0; c < 4; ++c) {
        int n = start + c * 64 + lane;
        int mt = (n < N) ? type_vec[n] : NT;
        #pragma unroll
        for (int t = 0; t < NT; ++t)
            cnt[t] += __popcll(__ballot(mt == t));
    }
    if (lane < NT) pb[wv][lane] = cnt[lane];
    __syncthreads();
    // block aggregate: one atomic per type, per-wave prefix redistribution
    if (tid < NT) {
        int s0 = pb[0][tid], s1 = pb[1][tid], s2 = pb[2][tid], s3 = pb[3][tid];
        int base = atomicAdd(&cursor[tid * 16], s0 + s1 + s2 + s3);
        pb[0][tid] = base;
        pb[1][tid] = base + s0;
        pb[2][tid] = base + s0 + s1;
        pb[3][tid] = base + s0 + s1 + s2;
    }
    __syncthreads();
    int run[NT];
    #pragma unroll
    for (int t = 0; t < NT; ++t) run[t] = seg[t] + pb[wv][t];

    // pass 2: rank within wave chunk, scatter
    unsigned long long below = (1ULL << lane) - 1ULL;
    #pragma unroll
    for (int c = 0; c < 4; ++c) {
        int n = start + c * 64 + lane;
        int mt = (n < N) ? type_vec[n] : NT;
        int mypos = 0;
        #pragma unroll
        for (int t = 0; t < NT; ++t) {
            unsigned long long msk = __ballot(mt == t);
            if (mt == t) mypos = run[t] + __popcll(msk & below);
            run[t] += __popcll(msk);
        }
        if (n < N) idx[mypos] = n;
    }
}

// ---------------------------------------------------------------------------
// K5: persistent chunked GEMM. 2048 blocks x 256 threads (4 waves);
//     each block owns `chunk` CONTIGUOUS 64-row tiles (usually one type).
//     B (32 KB) + bias staged once per type-run; steady loop is
//     BARRIER-FREE: cvt prefetched A -> issue next-tile idx/A loads
//     (hidden under MFMA+stores) -> MFMA from swizzled LDS -> direct
//     stores -> prefetch next node_c. Type boundary (rare): barrier,
//     restage B, barrier. launch_bounds(256,4): VGPR<=128 (est ~110),
//     4 blocks/CU (LDS 128 KB).
// ---------------------------------------------------------------------------
__global__ __launch_bounds__(256, 4) void k5_gemm(
    const float* __restrict__ x, const int* __restrict__ idx,
    const short* __restrict__ Wt, const float* __restrict__ Bias,
    const int* __restrict__ hist, float* __restrict__ out,
    int chunk)
{
    __shared__ short Bs[C * C];              // 32 KB
    int tid = threadIdx.x;
    int lane = tid & 63, w = tid >> 6;       // wave 0..3
    int m16 = lane & 15, quad = lane >> 4;

    int seg[NT + 1], harr[NT];
    {
        int s = 0;
        #pragma unroll
        for (int t = 0; t < NT; ++t) {
            harr[t] = hist[t];
            seg[t] = s;
            s += ((harr[t] + 63) >> 6) << 6;
        }
        seg[NT] = s;
    }
    int ntiles = seg[NT] >> 6;
    int tile0 = blockIdx.x * chunk;
    int tile1 = tile0 + chunk; if (tile1 > ntiles) tile1 = ntiles;
    if (tile0 >= tile1) return;

    float bv[8];
    float4 pa0[4], pa1[4];
    int pnodeC[4];

    auto typeOf = [&](int tile) {
        int bb = tile << 6, t = 0;
        #pragma unroll
        for (int i = 1; i < NT; ++i) if (bb >= seg[i]) t = i;
        return t;
    };
    auto vlimOf = [&](int t) {
        int v = 0;
        #pragma unroll
        for (int i = 0; i < NT; ++i) if (i == t) v = seg[i] + harr[i];
        return v;
    };
    auto stageB = [&](int t) {
        const short* wsrc = Wt + t * (C * C);
        short8 bstg[8];
        #pragma unroll
        for (int i = 0; i < 8; ++i)
            bstg[i] = *(const short8*)(wsrc + (size_t)(i * 256 + tid) * 8);
        #pragma unroll
        for (int i = 0; i < 8; ++i) {
            int s = i * 256 + tid;
            int row = s >> 4, sl = s & 15;
            *(short8*)((char*)Bs + row * 256 + ((sl ^ (row & 15)) << 4)) = bstg[i];
        }
        #pragma unroll
        for (int ni = 0; ni < 8; ++ni) bv[ni] = Bias[t * C + ni * 16 + m16];
    };
    auto prefA = [&](int tile, int vlim) {
        int rA = (tile << 6) + 16 * w + m16;
        int na = (rA < vlim) ? idx[rA] : 0;
        const float* xr = x + (size_t)na * C + quad * 8;
        #pragma unroll
        for (int kk = 0; kk < 4; ++kk) {
            pa0[kk] = *(const float4*)(xr + kk * 32);
            pa1[kk] = *(const float4*)(xr + kk * 32 + 4);
        }
    };
    auto prefC = [&](int tile) {
        int r0 = (tile << 6) + 16 * w + quad * 4;
        #pragma unroll
        for (int r = 0; r < 4; ++r) pnodeC[r] = idx[r0 + r];
    };

    int cur_t = typeOf(tile0);
    int cur_vlim = vlimOf(cur_t);
    stageB(cur_t);
    prefA(tile0, cur_vlim);
    prefC(tile0);
    __syncthreads();                         // B in LDS; steady loop barrier-free

    int tile = tile0;
    while (true) {
        // ---- consume prefetched A: cvt to bf16 fragments ----
        short8 af[4];
        #pragma unroll
        for (int kk = 0; kk < 4; ++kk) {
            short8 sv;
            sv[0] = f2bf(pa0[kk].x); sv[1] = f2bf(pa0[kk].y);
            sv[2] = f2bf(pa0[kk].z); sv[3] = f2bf(pa0[kk].w);
            sv[4] = f2bf(pa1[kk].x); sv[5] = f2bf(pa1[kk].y);
            sv[6] = f2bf(pa1[kk].z); sv[7] = f2bf(pa1[kk].w);
            af[kk] = sv;
        }
        if (((tile << 6) + 16 * w + m16) >= cur_vlim) {
            #pragma unroll
            for (int kk = 0; kk < 4; ++kk)
                af[kk] = (short8){0, 0, 0, 0, 0, 0, 0, 0};
        }

        int next = tile + 1;
        bool have = next < tile1;
        int nt_ = have ? typeOf(next) : cur_t;
        bool same = have && (nt_ == cur_t);
        if (same) prefA(next, cur_vlim);     // hidden under MFMA+stores

        // ---- MFMA from swizzled LDS ----
        f32x4 acc[8];
        #pragma unroll
        for (int i = 0; i < 8; ++i) acc[i] = (f32x4){0.f, 0.f, 0.f, 0.f};
        {
            const char* bbase = (const char*)Bs + m16 * 256;
            #pragma unroll
            for (int kk = 0; kk < 4; ++kk) {
                int cswz = (((kk * 4 + quad) ^ m16) << 4);
                #pragma unroll
                for (int ni = 0; ni < 8; ++ni) {
                    short8 bf = *(const short8*)(bbase + (ni << 12) + cswz);
                    acc[ni] = __builtin_amdgcn_mfma_f32_16x16x32_bf16(af[kk], bf, acc[ni], 0, 0, 0);
                }
            }
        }

        // ---- stores: 16-lane groups write 64B contiguous per (ni, r) ----
        {
            int rbase = (tile << 6) + 16 * w + quad * 4;
            #pragma unroll
            for (int ni = 0; ni < 8; ++ni) {
                #pragma unroll
                for (int r = 0; r < 4; ++r) {
                    if (rbase + r < cur_vlim)
                        out[(size_t)pnodeC[r] * C + ni * 16 + m16] = acc[ni][r] + bv[ni];
                }
            }
        }

        if (!have) break;
        if (same) {
            prefC(next);                     // pnodeC consumed by stores above
        } else {
            __syncthreads();                 // all waves done reading old B
            stageB(nt_);
            cur_t = nt_; cur_vlim = vlimOf(nt_);
            __syncthreads();
            prefA(next, cur_vlim);           // rare exposed chain
            prefC(next);
        }
        tile = next;
    }
}

// ---------------------------------------------------------------------------
extern "C" void kernel_launch(void* const* d_in, const int* in_sizes, int n_in,
                              void* d_out, int out_size, void* d_ws, size_t ws_size,
                              hipStream_t stream)
{
    const float* x         = (const float*)d_in[0];
    const int*   type_vec  = (const int*)d_in[1];
    const float* edge_feas = (const float*)d_in[2];
    const float* wg_w1 = (const float*)d_in[3];
    const float* wg_b1 = (const float*)d_in[4];
    const float* wg_w2 = (const float*)d_in[5];
    const float* wg_b2 = (const float*)d_in[6];
    const float* wg_w3 = (const float*)d_in[7];
    const float* wg_b3 = (const float*)d_in[8];
    const float* bg_w1 = (const float*)d_in[9];
    const float* bg_b1 = (const float*)d_in[10];
    const float* bg_w2 = (const float*)d_in[11];
    const float* bg_b2 = (const float*)d_in[12];
    const float* bg_w3 = (const float*)d_in[13];
    const float* bg_b3 = (const float*)d_in[14];
    float* out = (float*)d_out;
    int N = in_sizes[1];

    char* ws = (char*)d_ws;
    int*   hist   = (int*)(ws + 0);        // 8 ints
    int*   cursor = (int*)(ws + 128);      // 8 ints, 64B stride
    float* h_wg   = (float*)(ws + 1024);   // 8*256 f32
    float* h_bg   = (float*)(ws + 9216);   // 8*256 f32
    float* Bias   = (float*)(ws + 17408);  // 8*128 f32
    short* Wt     = (short*)(ws + 21504);  // 8*128*128 bf16 [t][n][k] (ends 283648)
    int*   idx    = (int*)(ws + 283648);   // (nblk64+8)*64 ints, NOT pre-initialized

    int nblk64  = (N + 63) / 64;
    int n_hist  = (N + 1023) / 1024;
    int max_tiles = nblk64 + 8;            // upper bound incl. per-type pad
    int G = 2048;
    int chunk = (max_tiles + G - 1) / G;

    k1_init_genh<<<17, 256, 0, stream>>>(
        edge_feas, wg_w1, wg_b1, wg_w2, wg_b2, bg_w1, bg_b1, bg_w2, bg_b2,
        hist, cursor, h_wg, h_bg);

    k2_hist_genw<<<n_hist + 257, 256, 0, stream>>>(
        type_vec, N, h_wg, h_bg, wg_w3, wg_b3, bg_w3, bg_b3,
        hist, Wt, Bias, n_hist);

    k4_scatter<<<n_hist, 256, 0, stream>>>(
        type_vec, N, hist, cursor, idx);

    k5_gemm<<<G, 256, 0, stream>>>(x, idx, Wt, Bias, hist, out, chunk);
}